// Round 9
// baseline (7385.980 us; speedup 1.0000x reference)
//
#include <hip/hip_runtime.h>
#include <hip/hip_bf16.h>
#include <math.h>

// ---------------------------------------------------------------------------
// Round 9: kill the flag-polling storm.
//  - Per-layer aggregated monotonic counters (device-scope atomicAdd fan-in,
//    one add per block per step). Consumers poll ONE word per dependency.
//  - <=3 poller threads per block (tid 0/64/128: separate waves), s_sleep(8).
//  - r5-proven coherence: sc0sc1 write-through h-stores + sc0sc1 h-loads,
//    NO periodic L2 invalidation.
//  - All dependency waits hoisted to one block per step; L1 issues both
//    GEMM regions' loads in one rolling vmcnt pipeline.
// Blocks: [0,64) L0 16-col, [64,192) L1 8-col, [192,196) FC. 256 thr.
// ---------------------------------------------------------------------------

#define S_LEN 512
#define B_SZ  64
#define V_SZ  128
#define H_SZ  1024
#define BH    65536
#define RING  32
#define SLOT  66560          // BH + 1024 u16 pad
#define FSTR  16             // ints per counter slot (64B)
#define WSTR  1040           // LDS weight row stride (u16)

typedef unsigned short u16;
typedef unsigned short u16x8 __attribute__((ext_vector_type(8)));
typedef __bf16         bf16x8 __attribute__((ext_vector_type(8)));
typedef float          f32x4  __attribute__((ext_vector_type(4)));
typedef int            i32x4  __attribute__((ext_vector_type(4)));

__device__ __forceinline__ u16 f2bf(float f) {
    unsigned int u = __float_as_uint(f);
    u += 0x7fffu + ((u >> 16) & 1u);
    return (u16)(u >> 16);
}
__device__ __forceinline__ f32x4 mfma16(u16x8 a, u16x8 b, f32x4 c) {
    return __builtin_amdgcn_mfma_f32_16x16x32_bf16(
        __builtin_bit_cast(bf16x8, a), __builtin_bit_cast(bf16x8, b), c, 0, 0, 0);
}
__device__ __forceinline__ f32x4 mfma16(i32x4 a, u16x8 b, f32x4 c) {
    return __builtin_amdgcn_mfma_f32_16x16x32_bf16(
        __builtin_bit_cast(bf16x8, a), __builtin_bit_cast(bf16x8, b), c, 0, 0, 0);
}

// coherent (L1/L2-bypass) load for h-state: reads the coherence point
__device__ __forceinline__ void ld_cv(i32x4& d, const u16* p) {
    asm volatile("global_load_dwordx4 %0, %1, off sc0 sc1" : "=v"(d) : "v"(p));
}
// plain cached load for immutable data (x)
__device__ __forceinline__ void ld_ca(i32x4& d, const u16* p) {
    asm volatile("global_load_dwordx4 %0, %1, off" : "=v"(d) : "v"(p));
}
// coherent write-through h store (round-5-proven)
__device__ __forceinline__ void st_coh16(u16* p, u16x8 v) {
    i32x4 vv = __builtin_bit_cast(i32x4, v);
    asm volatile("global_store_dwordx4 %0, %1, off sc0 sc1" :: "v"(p), "v"(vv));
}
__device__ __forceinline__ int ld_flag(const int* p) {
    int v;
    asm volatile("global_load_dword %0, %1, off sc0 sc1\n\ts_waitcnt vmcnt(0)"
                 : "=v"(v) : "v"(p) : "memory");
    return v;
}
__device__ __forceinline__ void wait_ge(const int* p, int tgt) {
    while (ld_flag(p) < tgt) __builtin_amdgcn_s_sleep(8);
}
#define WAITV(n) asm volatile("s_waitcnt vmcnt(" #n ")" ::: "memory")
#define LGKM0    asm volatile("s_waitcnt lgkmcnt(0)" ::: "memory")
#define SCHEDB   __builtin_amdgcn_sched_barrier(0)

__global__ __launch_bounds__(256) void cvt_kernel(const float* __restrict__ s,
                                                  u16* __restrict__ d, int n)
{
    int i = (blockIdx.x * 256 + threadIdx.x) * 4;
    if (i >= n) return;
    float4 v = *(const float4*)(s + i);
    ushort4 o;
    o.x = f2bf(v.x); o.y = f2bf(v.y); o.z = f2bf(v.z); o.w = f2bf(v.w);
    *(ushort4*)(d + i) = o;
}

union SMemL {
    struct { u16 whh[64 * WSTR]; u16 wih[64 * 144]; u16 tr[4][384]; } l0; // 154.6KB
    struct { u16 w[64 * WSTR]; u16 tr[4][384]; } l1;                      // 136.2KB
    float lg[16][132];
};

__global__ __launch_bounds__(256, 1) void persist_kernel(
    const u16* __restrict__ xb,
    const u16* __restrict__ Wih0c, const u16* __restrict__ Whh0c,
    const u16* __restrict__ Wih1c, const u16* __restrict__ Whh1c,
    const u16* __restrict__ Wfcc,
    const float* __restrict__ bih0, const float* __restrict__ bhh0,
    const float* __restrict__ bih1, const float* __restrict__ bhh1,
    const float* __restrict__ bfc,
    u16* __restrict__ h0b, u16* __restrict__ h1b,
    int* __restrict__ cntL0, int* __restrict__ cntL1, int* __restrict__ cntFC,
    float* __restrict__ out)
{
    __shared__ SMemL sm;
    const int bid = blockIdx.x, tid = threadIdx.x;
    const int wave = tid >> 6, lane = tid & 63;
    const int l16 = lane & 15, kgi = lane >> 4, kg8 = kgi * 8;

    // ======================= LAYER 0 : blocks 0..63 =======================
    if (bid < 64) {
        const int j0 = bid * 16, jj = j0 + l16;
        for (int ch = tid; ch < 1024; ch += 256) {          // Wih0 [64 rows][128]
            int row = ch >> 4, kc = ch & 15;
            int gr = (row >> 4) * H_SZ + j0 + (row & 15);
            *(u16x8*)&sm.l0.wih[row * 144 + kc * 8] =
                *(const u16x8*)(Wih0c + (size_t)gr * V_SZ + kc * 8);
        }
        for (int ch = tid; ch < 8192; ch += 256) {          // Whh0 [64 rows][1024]
            int row = ch >> 7, kc = ch & 127;
            int gr = (row >> 4) * H_SZ + j0 + (row & 15);
            *(u16x8*)&sm.l0.whh[row * WSTR + kc * 8] =
                *(const u16x8*)(Whh0c + (size_t)gr * H_SZ + kc * 8);
        }
        __syncthreads();

        const float bii = bih0[jj]            + bhh0[jj];
        const float bif = bih0[H_SZ + jj]     + bhh0[H_SZ + jj];
        const float big = bih0[2 * H_SZ + jj] + bhh0[2 * H_SZ + jj];
        const float bio = bih0[3 * H_SZ + jj] + bhh0[3 * H_SZ + jj];

        int whh_b[4], wih_b[4];
        #pragma unroll
        for (int g = 0; g < 4; ++g) {
            whh_b[g] = (g * 16 + l16) * WSTR + kg8;
            wih_b[g] = (g * 16 + l16) * 144 + kg8;
        }
        const int arow = wave * 16 + l16;
        const u16* xrow = xb + (size_t)arow * (S_LEN * V_SZ);
        u16* trw = sm.l0.tr[wave];
        float creg[4] = {0.f, 0.f, 0.f, 0.f};

        for (int t = 0; t < S_LEN; ++t) {
            // x prefetch (independent of flags)
            i32x4 xq[4];
            {
                const u16* xp = xrow + (size_t)t * V_SZ + kg8;
                #pragma unroll
                for (int i = 0; i < 4; ++i) ld_ca(xq[i], xp + i * 32);
            }
            // waits: all-L0 done t-1; WAR: all-L1 done t-RING
            if (tid == 0 && t >= 1)
                wait_ge(cntL0 + ((t - 1) & 31) * FSTR, 64 * (((t - 1) >> 5) + 1));
            if (tid == 64 && t >= RING)
                wait_ge(cntL1 + (t & 31) * FSTR, 128 * (t >> 5));
            __syncthreads();
            WAITV(0); SCHEDB;                               // xq valid for all lanes

            f32x4 acc[4][2] = {};
            auto ISSUE = [&](i32x4 (&buf)[8], const u16* base) {
                #pragma unroll
                for (int q = 0; q < 8; ++q) ld_cv(buf[q], base + q * 32);
            };
            auto COMP = [&](i32x4 (&buf)[8], int k0) {
                #pragma unroll
                for (int q = 0; q < 8; ++q)
                    #pragma unroll
                    for (int g = 0; g < 4; ++g)
                        acc[g][q & 1] = mfma16(buf[q],
                            *(const u16x8*)&sm.l0.whh[whh_b[g] + (k0 + q) * 32],
                            acc[g][q & 1]);
            };
            const u16* aB = h0b + (size_t)((t - 1) & (RING - 1)) * SLOT
                          + (size_t)arow * H_SZ + kg8;
            i32x4 b0[8], b1[8], b2[8];
            ISSUE(b0, aB); ISSUE(b1, aB + 256); ISSUE(b2, aB + 512);
            SCHEDB;
            #pragma unroll
            for (int i = 0; i < 4; ++i)
                #pragma unroll
                for (int g = 0; g < 4; ++g)
                    acc[g][i & 1] = mfma16(xq[i],
                        *(const u16x8*)&sm.l0.wih[wih_b[g] + i * 32], acc[g][i & 1]);
            WAITV(16); SCHEDB; COMP(b0, 0);  ISSUE(b0, aB + 768);
            WAITV(16); SCHEDB; COMP(b1, 8);
            WAITV(8);  SCHEDB; COMP(b2, 16);
            WAITV(0);  SCHEDB; COMP(b0, 24);

            // fused LSTM update -> LDS mini-transpose -> 16B coherent stores
            {
                u16* hout = h0b + (size_t)(t & (RING - 1)) * SLOT;
                #pragma unroll
                for (int r = 0; r < 4; ++r) {
                    const float ip = acc[0][0][r] + acc[0][1][r] + bii;
                    const float fp = acc[1][0][r] + acc[1][1][r] + bif;
                    const float gp = acc[2][0][r] + acc[2][1][r] + big;
                    const float op = acc[3][0][r] + acc[3][1][r] + bio;
                    const float iv = 1.f / (1.f + expf(-ip));
                    const float fv = 1.f / (1.f + expf(-fp));
                    const float gv = tanhf(gp);
                    const float ov = 1.f / (1.f + expf(-op));
                    const float cv = fv * creg[r] + iv * gv;
                    creg[r] = cv;
                    trw[(kgi * 4 + r) * 24 + l16] = f2bf(ov * tanhf(cv));
                }
                LGKM0; SCHEDB;
                if (lane < 32) {
                    int m = lane >> 1, jb = lane & 1;
                    u16x8 v = *(const u16x8*)&trw[m * 24 + jb * 8];
                    st_coh16(hout + (size_t)(wave * 16 + m) * H_SZ + j0 + jb * 8, v);
                }
                WAITV(0);
            }
            __syncthreads();
            if (tid == 0) atomicAdd(cntL0 + (t & 31) * FSTR, 1);
        }
        return;
    }

    // ======================= LAYER 1 : blocks 64..191 =======================
    if (bid < 192) {
        const int lb = bid - 64, j0 = lb * 8, jj2 = j0 + (l16 & 7);
        for (int ch = tid; ch < 8192; ch += 256) {
            int ldsrow = ch >> 7, kc = ch & 127;
            int region = ldsrow >> 5, rl = ldsrow & 31;
            int gr = (rl >> 3) * H_SZ + j0 + (rl & 7);
            const u16* src = (region ? Whh1c : Wih1c) + (size_t)gr * H_SZ + kc * 8;
            *(u16x8*)&sm.l1.w[ldsrow * WSTR + kc * 8] = *(const u16x8*)src;
        }
        __syncthreads();

        const float bii = bih1[jj2]            + bhh1[jj2];
        const float bif = bih1[H_SZ + jj2]     + bhh1[H_SZ + jj2];
        const float big = bih1[2 * H_SZ + jj2] + bhh1[2 * H_SZ + jj2];
        const float bio = bih1[3 * H_SZ + jj2] + bhh1[3 * H_SZ + jj2];
        const bool lo = (l16 < 8);

        int wrb[2][2];
        #pragma unroll
        for (int region = 0; region < 2; ++region)
            #pragma unroll
            for (int nt = 0; nt < 2; ++nt)
                wrb[region][nt] = (region * 32 + nt * 16 + l16) * WSTR + kg8;
        const int arow = wave * 16 + l16;
        u16* trw = sm.l1.tr[wave];
        float creg[4] = {0.f, 0.f, 0.f, 0.f};

        for (int t = 0; t < S_LEN; ++t) {
            // waits: L0 done t; all-L1 done t-1; WAR: FC done t-RING
            if (tid == 0)
                wait_ge(cntL0 + (t & 31) * FSTR, 64 * ((t >> 5) + 1));
            if (tid == 64 && t >= 1)
                wait_ge(cntL1 + ((t - 1) & 31) * FSTR, 128 * (((t - 1) >> 5) + 1));
            if (tid == 128 && t >= RING)
                wait_ge(cntFC + (t & 31) * FSTR, 4 * (t >> 5));
            __syncthreads();

            f32x4 acc[2][2] = {};
            auto ISSUE = [&](i32x4 (&buf)[8], const u16* base) {
                #pragma unroll
                for (int q = 0; q < 8; ++q) ld_cv(buf[q], base + q * 32);
            };
            auto COMP = [&](i32x4 (&buf)[8], int region, int k0) {
                #pragma unroll
                for (int q = 0; q < 8; ++q)
                    #pragma unroll
                    for (int nt = 0; nt < 2; ++nt)
                        acc[nt][q & 1] = mfma16(buf[q],
                            *(const u16x8*)&sm.l1.w[wrb[region][nt] + (k0 + q) * 32],
                            acc[nt][q & 1]);
            };
            const u16* a1 = h0b + (size_t)(t & (RING - 1)) * SLOT + (size_t)arow * H_SZ + kg8;
            const u16* a2 = h1b + (size_t)((t - 1) & (RING - 1)) * SLOT + (size_t)arow * H_SZ + kg8;
            i32x4 b0[8], b1[8], b2[8];
            ISSUE(b0, a1); ISSUE(b1, a1 + 256); ISSUE(b2, a1 + 512);
            SCHEDB;
            WAITV(16); SCHEDB; COMP(b0, 0, 0);  ISSUE(b0, a1 + 768);
            WAITV(16); SCHEDB; COMP(b1, 0, 8);  ISSUE(b1, a2);
            WAITV(16); SCHEDB; COMP(b2, 0, 16); ISSUE(b2, a2 + 256);
            WAITV(16); SCHEDB; COMP(b0, 0, 24); ISSUE(b0, a2 + 512);
            WAITV(16); SCHEDB; COMP(b1, 1, 0);  ISSUE(b1, a2 + 768);
            WAITV(16); SCHEDB; COMP(b2, 1, 8);
            WAITV(8);  SCHEDB; COMP(b0, 1, 16);
            WAITV(0);  SCHEDB; COMP(b1, 1, 24);

            // epilogue: tile0=(i|f), tile1=(g|o); pair exchange; transpose-store
            {
                #pragma unroll
                for (int r = 0; r < 4; ++r) {
                    const float s0 = acc[0][0][r] + acc[0][1][r];
                    const float s1 = acc[1][0][r] + acc[1][1][r];
                    const float q0 = __shfl_xor(s0, 8);
                    const float q1 = __shfl_xor(s1, 8);
                    const float ip = (lo ? s0 : q0) + bii;
                    const float fp = (lo ? q0 : s0) + bif;
                    const float gp = (lo ? s1 : q1) + big;
                    const float op = (lo ? q1 : s1) + bio;
                    const float iv = 1.f / (1.f + expf(-ip));
                    const float fv = 1.f / (1.f + expf(-fp));
                    const float gv = tanhf(gp);
                    const float ov = 1.f / (1.f + expf(-op));
                    const float cv = fv * creg[r] + iv * gv;
                    creg[r] = cv;
                    if (lo) trw[(kgi * 4 + r) * 24 + (l16 & 7)] = f2bf(ov * tanhf(cv));
                }
                LGKM0; SCHEDB;
                if (lane < 16) {
                    int m = lane;
                    u16x8 v = *(const u16x8*)&trw[m * 24];
                    st_coh16(h1b + (size_t)(t & (RING - 1)) * SLOT
                             + (size_t)(wave * 16 + m) * H_SZ + j0, v);
                }
                WAITV(0);
            }
            __syncthreads();
            if (tid == 0) atomicAdd(cntL1 + (t & 31) * FSTR, 1);
        }
        return;
    }

    // ======================= FC : blocks 192..195 =======================
    {
        const int fb = bid - 192, m0 = fb * 16;
        const u16* wp[2];
        #pragma unroll
        for (int nt = 0; nt < 2; ++nt)
            wp[nt] = Wfcc + (size_t)(wave * 32 + nt * 16 + l16) * H_SZ + kg8;

        for (int t = 0; t < S_LEN; ++t) {
            if (tid == 0)
                wait_ge(cntL1 + (t & 31) * FSTR, 128 * ((t >> 5) + 1));
            __syncthreads();

            const u16* aB = h1b + (size_t)(t & (RING - 1)) * SLOT
                          + (size_t)(m0 + l16) * H_SZ + kg8;
            f32x4 acc[2][2] = {};
            i32x4 buf[8];
            #pragma unroll
            for (int c = 0; c < 4; ++c) {
                #pragma unroll
                for (int q = 0; q < 8; ++q) ld_cv(buf[q], aB + c * 256 + q * 32);
                WAITV(0); SCHEDB;
                #pragma unroll
                for (int q = 0; q < 8; ++q) {
                    #pragma unroll
                    for (int nt = 0; nt < 2; ++nt)
                        acc[nt][q & 1] = mfma16(buf[q],
                            *(const u16x8*)(wp[nt] + (c * 8 + q) * 32), acc[nt][q & 1]);
                }
            }
            #pragma unroll
            for (int nt = 0; nt < 2; ++nt)
                #pragma unroll
                for (int r = 0; r < 4; ++r) {
                    const int m = kgi * 4 + r, n = wave * 32 + nt * 16 + l16;
                    sm.lg[m][n] = acc[nt][0][r] + acc[nt][1][r] + bfc[n];
                }
            __syncthreads();
            const int row = tid >> 4, sub = tid & 15;
            float vals[8]; float mx = -1e30f;
            #pragma unroll
            for (int q = 0; q < 8; ++q) { vals[q] = sm.lg[row][sub * 8 + q]; mx = fmaxf(mx, vals[q]); }
            #pragma unroll
            for (int o = 1; o < 16; o <<= 1) mx = fmaxf(mx, __shfl_xor(mx, o));
            float se = 0.f;
            #pragma unroll
            for (int q = 0; q < 8; ++q) se += expf(vals[q] - mx);
            #pragma unroll
            for (int o = 1; o < 16; o <<= 1) se += __shfl_xor(se, o);
            const float ls = mx + logf(se);
            float* op = out + (size_t)(m0 + row) * (S_LEN * V_SZ) + (size_t)t * V_SZ + sub * 8;
            #pragma unroll
            for (int q = 0; q < 8; ++q) op[q] = vals[q] - ls;

            __syncthreads();
            if (tid == 0) atomicAdd(cntFC + (t & 31) * FSTR, 1);
        }
    }
}

// =============================== launcher ==================================
extern "C" void kernel_launch(void* const* d_in, const int* in_sizes, int n_in,
                              void* d_out, int out_size, void* d_ws, size_t ws_size,
                              hipStream_t stream)
{
    const float* x    = (const float*)d_in[0];
    const float* Wih0 = (const float*)d_in[1];
    const float* Whh0 = (const float*)d_in[2];
    const float* bih0 = (const float*)d_in[3];
    const float* bhh0 = (const float*)d_in[4];
    const float* Wih1 = (const float*)d_in[5];
    const float* Whh1 = (const float*)d_in[6];
    const float* bih1 = (const float*)d_in[7];
    const float* bhh1 = (const float*)d_in[8];
    const float* Wfc  = (const float*)d_in[9];
    const float* bfc  = (const float*)d_in[10];
    float* out = (float*)d_out;

    u16* wih0 = (u16*)d_ws;
    u16* whh0 = wih0 + (size_t)4096 * 128;
    u16* wih1 = whh0 + (size_t)4096 * 1024;
    u16* whh1 = wih1 + (size_t)4096 * 1024;
    u16* wfc  = whh1 + (size_t)4096 * 1024;
    u16* xbuf = wfc  + (size_t)128 * 1024;
    u16* h0b  = xbuf + (size_t)B_SZ * S_LEN * V_SZ;
    u16* h1b  = h0b + (size_t)RING * SLOT;
    int* cnts  = (int*)(h1b + (size_t)RING * SLOT);          // 3*RING*FSTR ints
    int* cntL0 = cnts;
    int* cntL1 = cntL0 + RING * FSTR;
    int* cntFC = cntL1 + RING * FSTR;

    auto cvt = [&](const float* s, u16* d, int n) {
        cvt_kernel<<<(n / 4 + 255) / 256, 256, 0, stream>>>(s, d, n);
    };
    cvt(Wih0, wih0, 4096 * 128);
    cvt(Whh0, whh0, 4096 * 1024);
    cvt(Wih1, wih1, 4096 * 1024);
    cvt(Whh1, whh1, 4096 * 1024);
    cvt(Wfc,  wfc,  128 * 1024);
    cvt(x,    xbuf, B_SZ * S_LEN * V_SZ);
    hipMemsetAsync(h0b + (size_t)(RING - 1) * SLOT, 0, (size_t)BH * sizeof(u16), stream);
    hipMemsetAsync(h1b + (size_t)(RING - 1) * SLOT, 0, (size_t)BH * sizeof(u16), stream);
    hipMemsetAsync(cnts, 0, (size_t)3 * RING * FSTR * sizeof(int), stream);

    persist_kernel<<<196, 256, 0, stream>>>(
        xbuf, wih0, whh0, wih1, whh1, wfc,
        bih0, bhh0, bih1, bhh1, bfc,
        h0b, h1b, cntL0, cntL1, cntFC, out);
}

// Round 10
// 6777.931 us; speedup vs baseline: 1.0897x; 1.0897x over previous
//
#include <hip/hip_runtime.h>
#include <hip/hip_bf16.h>
#include <math.h>

// ---------------------------------------------------------------------------
// Round 10: hide handoff latency under compute.
//  - L1 computes Whh1*h1[t-1] FIRST (operand ready early); gates on h0[t]
//    MID-pipeline -> L0's drain/signal/detect hides under L1's first region.
//  - Per-wave ballot waits (__all over per-lane flag loads): no block barrier
//    at step top; only barrier left is the pre-signal store drain.
//  - L0's x-MFMA pass runs BEFORE its peer wait.
//  - h loads cached (L2-shared, 64B lines); h stores sc0sc1 write-through;
//    RING=32 + agent acquire fence every INVP=20 steps (r7-proven coherence).
// Blocks: [0,64) L0 16-col, [64,192) L1 8-col, [192,196) FC. 256 thr.
// ---------------------------------------------------------------------------

#define S_LEN 512
#define B_SZ  64
#define V_SZ  128
#define H_SZ  1024
#define BH    65536
#define RING  32
#define SLOT  66560          // BH + 1024 u16 pad
#define FSTR  16             // ints per flag slot (64B)
#define INVP  20
#define WSTR  1040           // LDS weight row stride (u16)

typedef unsigned short u16;
typedef unsigned short u16x8 __attribute__((ext_vector_type(8)));
typedef __bf16         bf16x8 __attribute__((ext_vector_type(8)));
typedef float          f32x4  __attribute__((ext_vector_type(4)));
typedef int            i32x4  __attribute__((ext_vector_type(4)));

__device__ __forceinline__ u16 f2bf(float f) {
    unsigned int u = __float_as_uint(f);
    u += 0x7fffu + ((u >> 16) & 1u);
    return (u16)(u >> 16);
}
__device__ __forceinline__ f32x4 mfma16(u16x8 a, u16x8 b, f32x4 c) {
    return __builtin_amdgcn_mfma_f32_16x16x32_bf16(
        __builtin_bit_cast(bf16x8, a), __builtin_bit_cast(bf16x8, b), c, 0, 0, 0);
}
__device__ __forceinline__ f32x4 mfma16(i32x4 a, u16x8 b, f32x4 c) {
    return __builtin_amdgcn_mfma_f32_16x16x32_bf16(
        __builtin_bit_cast(bf16x8, a), __builtin_bit_cast(bf16x8, b), c, 0, 0, 0);
}

// cached load (L2-shared path) for h / x
__device__ __forceinline__ void ld_ca(i32x4& d, const u16* p) {
    asm volatile("global_load_dwordx4 %0, %1, off" : "=v"(d) : "v"(p));
}
// coherent write-through h store (round-5-proven)
__device__ __forceinline__ void st_coh16(u16* p, u16x8 v) {
    i32x4 vv = __builtin_bit_cast(i32x4, v);
    asm volatile("global_store_dwordx4 %0, %1, off sc0 sc1" :: "v"(p), "v"(vv));
}
__device__ __forceinline__ int ld_flag(const int* p) {
    int v;
    asm volatile("global_load_dword %0, %1, off sc0 sc1\n\ts_waitcnt vmcnt(0)"
                 : "=v"(v) : "v"(p) : "memory");
    return v;
}
__device__ __forceinline__ void st_flag(int* p, int v) {
    asm volatile("global_store_dword %0, %1, off sc0 sc1" :: "v"(p), "v"(v));
}
// per-wave ballot poll: up to 3 per-lane (flag,target) pairs; null = satisfied
__device__ __forceinline__ void poll3(const int* p0, int t0,
                                      const int* p1, int t1,
                                      const int* p2, int t2) {
    for (;;) {
        bool ok = true;
        if (p0) ok = ok && (ld_flag(p0) >= t0);
        if (p1) ok = ok && (ld_flag(p1) >= t1);
        if (p2) ok = ok && (ld_flag(p2) >= t2);
        if (__all(ok)) break;
        __builtin_amdgcn_s_sleep(2);
    }
}
#define WAITV(n) asm volatile("s_waitcnt vmcnt(" #n ")" ::: "memory")
#define LGKM0    asm volatile("s_waitcnt lgkmcnt(0)" ::: "memory")
#define SCHEDB   __builtin_amdgcn_sched_barrier(0)

__device__ __forceinline__ void l2_acquire_inv() {
    __builtin_amdgcn_fence(__ATOMIC_ACQUIRE, "agent");
}

__global__ __launch_bounds__(256) void cvt_kernel(const float* __restrict__ s,
                                                  u16* __restrict__ d, int n)
{
    int i = (blockIdx.x * 256 + threadIdx.x) * 4;
    if (i >= n) return;
    float4 v = *(const float4*)(s + i);
    ushort4 o;
    o.x = f2bf(v.x); o.y = f2bf(v.y); o.z = f2bf(v.z); o.w = f2bf(v.w);
    *(ushort4*)(d + i) = o;
}

union SMemL {
    struct { u16 whh[64 * WSTR]; u16 wih[64 * 144]; u16 tr[4][384]; } l0; // 154.6KB
    struct { u16 w[64 * WSTR]; u16 tr[4][384]; } l1;                      // 136.2KB
    float lg[16][132];
};

__global__ __launch_bounds__(256, 1) void persist_kernel(
    const u16* __restrict__ xb,
    const u16* __restrict__ Wih0c, const u16* __restrict__ Whh0c,
    const u16* __restrict__ Wih1c, const u16* __restrict__ Whh1c,
    const u16* __restrict__ Wfcc,
    const float* __restrict__ bih0, const float* __restrict__ bhh0,
    const float* __restrict__ bih1, const float* __restrict__ bhh1,
    const float* __restrict__ bfc,
    u16* __restrict__ h0b, u16* __restrict__ h1b,
    int* __restrict__ flagL0, int* __restrict__ flagL1, int* __restrict__ flagFC,
    float* __restrict__ out)
{
    __shared__ SMemL sm;
    const int bid = blockIdx.x, tid = threadIdx.x;
    const int wave = tid >> 6, lane = tid & 63;
    const int l16 = lane & 15, kgi = lane >> 4, kg8 = kgi * 8;

    // ======================= LAYER 0 : blocks 0..63 =======================
    if (bid < 64) {
        const int j0 = bid * 16, jj = j0 + l16;
        for (int ch = tid; ch < 1024; ch += 256) {          // Wih0 [64 rows][128]
            int row = ch >> 4, kc = ch & 15;
            int gr = (row >> 4) * H_SZ + j0 + (row & 15);
            *(u16x8*)&sm.l0.wih[row * 144 + kc * 8] =
                *(const u16x8*)(Wih0c + (size_t)gr * V_SZ + kc * 8);
        }
        for (int ch = tid; ch < 8192; ch += 256) {          // Whh0 [64 rows][1024]
            int row = ch >> 7, kc = ch & 127;
            int gr = (row >> 4) * H_SZ + j0 + (row & 15);
            *(u16x8*)&sm.l0.whh[row * WSTR + kc * 8] =
                *(const u16x8*)(Whh0c + (size_t)gr * H_SZ + kc * 8);
        }
        __syncthreads();

        const float bii = bih0[jj]            + bhh0[jj];
        const float bif = bih0[H_SZ + jj]     + bhh0[H_SZ + jj];
        const float big = bih0[2 * H_SZ + jj] + bhh0[2 * H_SZ + jj];
        const float bio = bih0[3 * H_SZ + jj] + bhh0[3 * H_SZ + jj];

        int whh_b[4], wih_b[4];
        #pragma unroll
        for (int g = 0; g < 4; ++g) {
            whh_b[g] = (g * 16 + l16) * WSTR + kg8;
            wih_b[g] = (g * 16 + l16) * 144 + kg8;
        }
        const int arow = wave * 16 + l16;
        const u16* xrow = xb + (size_t)arow * (S_LEN * V_SZ);
        u16* trw = sm.l0.tr[wave];
        float creg[4] = {0.f, 0.f, 0.f, 0.f};

        for (int t = 0; t < S_LEN; ++t) {
            // x loads + x-MFMA pass BEFORE any dependency wait
            f32x4 acc[4][2] = {};
            {
                i32x4 xq[4];
                const u16* xp = xrow + (size_t)t * V_SZ + kg8;
                #pragma unroll
                for (int i = 0; i < 4; ++i) ld_ca(xq[i], xp + i * 32);
                WAITV(0); SCHEDB;
                #pragma unroll
                for (int i = 0; i < 4; ++i)
                    #pragma unroll
                    for (int g = 0; g < 4; ++g)
                        acc[g][i & 1] = mfma16(xq[i],
                            *(const u16x8*)&sm.l0.wih[wih_b[g] + i * 32], acc[g][i & 1]);
            }
            // per-wave wait: peers flagL0[lane]>=t; WAR flagL1 both halves >= t-31
            poll3((t >= 1)    ? flagL0 + lane * FSTR        : nullptr, t,
                  (t >= RING) ? flagL1 + lane * FSTR        : nullptr, t - (RING - 1),
                  (t >= RING) ? flagL1 + (64 + lane) * FSTR : nullptr, t - (RING - 1));
            if (t >= INVP && (t % INVP) == 0) l2_acquire_inv();

            auto ISSUE = [&](i32x4 (&buf)[8], const u16* base) {
                #pragma unroll
                for (int q = 0; q < 8; ++q) ld_ca(buf[q], base + q * 32);
            };
            auto COMP = [&](i32x4 (&buf)[8], int k0) {
                #pragma unroll
                for (int q = 0; q < 8; ++q)
                    #pragma unroll
                    for (int g = 0; g < 4; ++g)
                        acc[g][q & 1] = mfma16(buf[q],
                            *(const u16x8*)&sm.l0.whh[whh_b[g] + (k0 + q) * 32],
                            acc[g][q & 1]);
            };
            const u16* aB = h0b + (size_t)((t - 1) & (RING - 1)) * SLOT
                          + (size_t)arow * H_SZ + kg8;
            i32x4 b0[8], b1[8], b2[8];
            ISSUE(b0, aB); ISSUE(b1, aB + 256); ISSUE(b2, aB + 512);
            SCHEDB;
            WAITV(16); SCHEDB; COMP(b0, 0);  ISSUE(b0, aB + 768);
            WAITV(16); SCHEDB; COMP(b1, 8);
            WAITV(8);  SCHEDB; COMP(b2, 16);
            WAITV(0);  SCHEDB; COMP(b0, 24);

            // fused LSTM update -> LDS mini-transpose -> 16B coherent stores
            {
                u16* hout = h0b + (size_t)(t & (RING - 1)) * SLOT;
                #pragma unroll
                for (int r = 0; r < 4; ++r) {
                    const float ip = acc[0][0][r] + acc[0][1][r] + bii;
                    const float fp = acc[1][0][r] + acc[1][1][r] + bif;
                    const float gp = acc[2][0][r] + acc[2][1][r] + big;
                    const float op = acc[3][0][r] + acc[3][1][r] + bio;
                    const float iv = 1.f / (1.f + expf(-ip));
                    const float fv = 1.f / (1.f + expf(-fp));
                    const float gv = tanhf(gp);
                    const float ov = 1.f / (1.f + expf(-op));
                    const float cv = fv * creg[r] + iv * gv;
                    creg[r] = cv;
                    trw[(kgi * 4 + r) * 24 + l16] = f2bf(ov * tanhf(cv));
                }
                LGKM0; SCHEDB;
                if (lane < 32) {
                    int m = lane >> 1, jb = lane & 1;
                    u16x8 v = *(const u16x8*)&trw[m * 24 + jb * 8];
                    st_coh16(hout + (size_t)(wave * 16 + m) * H_SZ + j0 + jb * 8, v);
                }
                WAITV(0);
            }
            __syncthreads();
            if (tid == 0) st_flag(flagL0 + bid * FSTR, t + 1);
        }
        return;
    }

    // ======================= LAYER 1 : blocks 64..191 =======================
    if (bid < 192) {
        const int lb = bid - 64, j0 = lb * 8, jj2 = j0 + (l16 & 7);
        for (int ch = tid; ch < 8192; ch += 256) {   // rows 0..31 Wih1, 32..63 Whh1
            int ldsrow = ch >> 7, kc = ch & 127;
            int region = ldsrow >> 5, rl = ldsrow & 31;
            int gr = (rl >> 3) * H_SZ + j0 + (rl & 7);
            const u16* src = (region ? Whh1c : Wih1c) + (size_t)gr * H_SZ + kc * 8;
            *(u16x8*)&sm.l1.w[ldsrow * WSTR + kc * 8] = *(const u16x8*)src;
        }
        __syncthreads();

        const float bii = bih1[jj2]            + bhh1[jj2];
        const float bif = bih1[H_SZ + jj2]     + bhh1[H_SZ + jj2];
        const float big = bih1[2 * H_SZ + jj2] + bhh1[2 * H_SZ + jj2];
        const float bio = bih1[3 * H_SZ + jj2] + bhh1[3 * H_SZ + jj2];
        const bool lo = (l16 < 8);

        int wrb[2][2];
        #pragma unroll
        for (int region = 0; region < 2; ++region)
            #pragma unroll
            for (int nt = 0; nt < 2; ++nt)
                wrb[region][nt] = (region * 32 + nt * 16 + l16) * WSTR + kg8;
        const int arow = wave * 16 + l16;
        u16* trw = sm.l1.tr[wave];
        float creg[4] = {0.f, 0.f, 0.f, 0.f};

        for (int t = 0; t < S_LEN; ++t) {
            // per-wave wait: L1 peers (both halves) done t-1; WAR flagFC >= t-31
            poll3((t >= 1)    ? flagL1 + lane * FSTR        : nullptr, t,
                  (t >= 1)    ? flagL1 + (64 + lane) * FSTR : nullptr, t,
                  (t >= RING) ? flagFC + (lane & 3) * FSTR  : nullptr, t - (RING - 1));
            if (t >= INVP && (t % INVP) == 0) l2_acquire_inv();

            f32x4 acc[2][2] = {};
            auto ISSUE = [&](i32x4 (&buf)[8], const u16* base) {
                #pragma unroll
                for (int q = 0; q < 8; ++q) ld_ca(buf[q], base + q * 32);
            };
            auto COMP = [&](i32x4 (&buf)[8], int region, int k0) {
                #pragma unroll
                for (int q = 0; q < 8; ++q)
                    #pragma unroll
                    for (int nt = 0; nt < 2; ++nt)
                        acc[nt][q & 1] = mfma16(buf[q],
                            *(const u16x8*)&sm.l1.w[wrb[region][nt] + (k0 + q) * 32],
                            acc[nt][q & 1]);
            };
            const u16* a2 = h1b + (size_t)((t - 1) & (RING - 1)) * SLOT
                          + (size_t)arow * H_SZ + kg8;                 // h1[t-1]
            i32x4 b0[8], b1[8], b2[8];
            // region A: Whh1 * h1[t-1]  (ready at step top)
            ISSUE(b0, a2); ISSUE(b1, a2 + 256); ISSUE(b2, a2 + 512);
            SCHEDB;
            WAITV(16); SCHEDB; COMP(b0, 1, 0);  ISSUE(b0, a2 + 768);
            WAITV(16); SCHEDB; COMP(b1, 1, 8);
            WAITV(8);  SCHEDB; COMP(b2, 1, 16);
            WAITV(0);  SCHEDB; COMP(b0, 1, 24);
            // mid-pipeline gate: h0[t] ready (all 64 L0 signaled t+1)
            poll3(flagL0 + lane * FSTR, t + 1, nullptr, 0, nullptr, 0);
            // region B: Wih1 * h0[t]
            const u16* a1 = h0b + (size_t)(t & (RING - 1)) * SLOT
                          + (size_t)arow * H_SZ + kg8;
            ISSUE(b0, a1); ISSUE(b1, a1 + 256); ISSUE(b2, a1 + 512);
            SCHEDB;
            WAITV(16); SCHEDB; COMP(b0, 0, 0);  ISSUE(b0, a1 + 768);
            WAITV(16); SCHEDB; COMP(b1, 0, 8);
            WAITV(8);  SCHEDB; COMP(b2, 0, 16);
            WAITV(0);  SCHEDB; COMP(b0, 0, 24);

            // epilogue: tile0=(i|f), tile1=(g|o); pair exchange; transpose-store
            {
                #pragma unroll
                for (int r = 0; r < 4; ++r) {
                    const float s0 = acc[0][0][r] + acc[0][1][r];
                    const float s1 = acc[1][0][r] + acc[1][1][r];
                    const float q0 = __shfl_xor(s0, 8);
                    const float q1 = __shfl_xor(s1, 8);
                    const float ip = (lo ? s0 : q0) + bii;
                    const float fp = (lo ? q0 : s0) + bif;
                    const float gp = (lo ? s1 : q1) + big;
                    const float op = (lo ? q1 : s1) + bio;
                    const float iv = 1.f / (1.f + expf(-ip));
                    const float fv = 1.f / (1.f + expf(-fp));
                    const float gv = tanhf(gp);
                    const float ov = 1.f / (1.f + expf(-op));
                    const float cv = fv * creg[r] + iv * gv;
                    creg[r] = cv;
                    if (lo) trw[(kgi * 4 + r) * 24 + (l16 & 7)] = f2bf(ov * tanhf(cv));
                }
                LGKM0; SCHEDB;
                if (lane < 16) {
                    int m = lane;
                    u16x8 v = *(const u16x8*)&trw[m * 24];
                    st_coh16(h1b + (size_t)(t & (RING - 1)) * SLOT
                             + (size_t)(wave * 16 + m) * H_SZ + j0, v);
                }
                WAITV(0);
            }
            __syncthreads();
            if (tid == 0) st_flag(flagL1 + lb * FSTR, t + 1);
        }
        return;
    }

    // ======================= FC : blocks 192..195 =======================
    {
        const int fb = bid - 192, m0 = fb * 16;
        const u16* wp[2];
        #pragma unroll
        for (int nt = 0; nt < 2; ++nt)
            wp[nt] = Wfcc + (size_t)(wave * 32 + nt * 16 + l16) * H_SZ + kg8;

        for (int t = 0; t < S_LEN; ++t) {
            poll3(flagL1 + lane * FSTR, t + 1,
                  flagL1 + (64 + lane) * FSTR, t + 1, nullptr, 0);
            if (t >= INVP && (t % INVP) == 0) l2_acquire_inv();

            const u16* aB = h1b + (size_t)(t & (RING - 1)) * SLOT
                          + (size_t)(m0 + l16) * H_SZ + kg8;
            f32x4 acc[2][2] = {};
            i32x4 buf[8];
            #pragma unroll
            for (int c = 0; c < 4; ++c) {
                #pragma unroll
                for (int q = 0; q < 8; ++q) ld_ca(buf[q], aB + c * 256 + q * 32);
                WAITV(0); SCHEDB;
                #pragma unroll
                for (int q = 0; q < 8; ++q) {
                    #pragma unroll
                    for (int nt = 0; nt < 2; ++nt)
                        acc[nt][q & 1] = mfma16(buf[q],
                            *(const u16x8*)(wp[nt] + (c * 8 + q) * 32), acc[nt][q & 1]);
                }
            }
            #pragma unroll
            for (int nt = 0; nt < 2; ++nt)
                #pragma unroll
                for (int r = 0; r < 4; ++r) {
                    const int m = kgi * 4 + r, n = wave * 32 + nt * 16 + l16;
                    sm.lg[m][n] = acc[nt][0][r] + acc[nt][1][r] + bfc[n];
                }
            __syncthreads();
            const int row = tid >> 4, sub = tid & 15;
            float vals[8]; float mx = -1e30f;
            #pragma unroll
            for (int q = 0; q < 8; ++q) { vals[q] = sm.lg[row][sub * 8 + q]; mx = fmaxf(mx, vals[q]); }
            #pragma unroll
            for (int o = 1; o < 16; o <<= 1) mx = fmaxf(mx, __shfl_xor(mx, o));
            float se = 0.f;
            #pragma unroll
            for (int q = 0; q < 8; ++q) se += expf(vals[q] - mx);
            #pragma unroll
            for (int o = 1; o < 16; o <<= 1) se += __shfl_xor(se, o);
            const float ls = mx + logf(se);
            float* op = out + (size_t)(m0 + row) * (S_LEN * V_SZ) + (size_t)t * V_SZ + sub * 8;
            #pragma unroll
            for (int q = 0; q < 8; ++q) op[q] = vals[q] - ls;

            __syncthreads();
            if (tid == 0) st_flag(flagFC + fb * FSTR, t + 1);
        }
    }
}

// =============================== launcher ==================================
extern "C" void kernel_launch(void* const* d_in, const int* in_sizes, int n_in,
                              void* d_out, int out_size, void* d_ws, size_t ws_size,
                              hipStream_t stream)
{
    const float* x    = (const float*)d_in[0];
    const float* Wih0 = (const float*)d_in[1];
    const float* Whh0 = (const float*)d_in[2];
    const float* bih0 = (const float*)d_in[3];
    const float* bhh0 = (const float*)d_in[4];
    const float* Wih1 = (const float*)d_in[5];
    const float* Whh1 = (const float*)d_in[6];
    const float* bih1 = (const float*)d_in[7];
    const float* bhh1 = (const float*)d_in[8];
    const float* Wfc  = (const float*)d_in[9];
    const float* bfc  = (const float*)d_in[10];
    float* out = (float*)d_out;

    u16* wih0 = (u16*)d_ws;
    u16* whh0 = wih0 + (size_t)4096 * 128;
    u16* wih1 = whh0 + (size_t)4096 * 1024;
    u16* whh1 = wih1 + (size_t)4096 * 1024;
    u16* wfc  = whh1 + (size_t)4096 * 1024;
    u16* xbuf = wfc  + (size_t)128 * 1024;
    u16* h0b  = xbuf + (size_t)B_SZ * S_LEN * V_SZ;
    u16* h1b  = h0b + (size_t)RING * SLOT;
    int* flags  = (int*)(h1b + (size_t)RING * SLOT);
    int* flagL0 = flags;
    int* flagL1 = flagL0 + 64 * FSTR;
    int* flagFC = flagL1 + 128 * FSTR;

    auto cvt = [&](const float* s, u16* d, int n) {
        cvt_kernel<<<(n / 4 + 255) / 256, 256, 0, stream>>>(s, d, n);
    };
    cvt(Wih0, wih0, 4096 * 128);
    cvt(Whh0, whh0, 4096 * 1024);
    cvt(Wih1, wih1, 4096 * 1024);
    cvt(Whh1, whh1, 4096 * 1024);
    cvt(Wfc,  wfc,  128 * 1024);
    cvt(x,    xbuf, B_SZ * S_LEN * V_SZ);
    hipMemsetAsync(h0b + (size_t)(RING - 1) * SLOT, 0, (size_t)BH * sizeof(u16), stream);
    hipMemsetAsync(h1b + (size_t)(RING - 1) * SLOT, 0, (size_t)BH * sizeof(u16), stream);
    hipMemsetAsync(flags, 0, (size_t)196 * FSTR * sizeof(int), stream);

    persist_kernel<<<196, 256, 0, stream>>>(
        xbuf, wih0, whh0, wih1, whh1, wfc,
        bih0, bhh0, bih1, bhh1, bfc,
        h0b, h1b, flagL0, flagL1, flagFC, out);
}

// Round 11
// 6359.840 us; speedup vs baseline: 1.1613x; 1.0657x over previous
//
#include <hip/hip_runtime.h>
#include <hip/hip_bf16.h>
#include <math.h>

// ---------------------------------------------------------------------------
// Round 11: REGISTER-RESIDENT WEIGHTS via K-split waves.
//  Theory: all prior rounds were LDS-read-bound (~144 ds_read_b128/thread/step,
//  ~8-way conflicted => ~8.5us/step). Now each wave owns a K-quarter and holds
//  its weight fragments in VGPRs (128 VGPR); partial accumulators are summed
//  across waves via a small conflict-free LDS reduce (32 LDS ops/thread/step).
//  L1 wave specialization: waves 2/3 compute Whh1*h1[t-1] (ready at step top)
//  while waves 0/1 wait for h0[t] -> handoff hides under compute.
//  Everything else (flags, poll3, coherence, transpose-stores) from r5-r10.
// Blocks: [0,64) L0 16-col, [64,192) L1 8-col, [192,196) FC. 256 thr.
// ---------------------------------------------------------------------------

#define S_LEN 512
#define B_SZ  64
#define V_SZ  128
#define H_SZ  1024
#define BH    65536
#define RING  32
#define SLOT  66560          // BH + 1024 u16 pad
#define FSTR  16
#define INVP  20

typedef unsigned short u16;
typedef unsigned short u16x8 __attribute__((ext_vector_type(8)));
typedef __bf16         bf16x8 __attribute__((ext_vector_type(8)));
typedef float          f32x4  __attribute__((ext_vector_type(4)));
typedef int            i32x4  __attribute__((ext_vector_type(4)));

__device__ __forceinline__ u16 f2bf(float f) {
    unsigned int u = __float_as_uint(f);
    u += 0x7fffu + ((u >> 16) & 1u);
    return (u16)(u >> 16);
}
__device__ __forceinline__ f32x4 mfma16(u16x8 a, u16x8 b, f32x4 c) {
    return __builtin_amdgcn_mfma_f32_16x16x32_bf16(
        __builtin_bit_cast(bf16x8, a), __builtin_bit_cast(bf16x8, b), c, 0, 0, 0);
}
__device__ __forceinline__ f32x4 mfma16(i32x4 a, u16x8 b, f32x4 c) {
    return __builtin_amdgcn_mfma_f32_16x16x32_bf16(
        __builtin_bit_cast(bf16x8, a), __builtin_bit_cast(bf16x8, b), c, 0, 0, 0);
}

__device__ __forceinline__ void ld_ca(i32x4& d, const u16* p) {
    asm volatile("global_load_dwordx4 %0, %1, off" : "=v"(d) : "v"(p));
}
__device__ __forceinline__ void st_coh16(u16* p, u16x8 v) {
    i32x4 vv = __builtin_bit_cast(i32x4, v);
    asm volatile("global_store_dwordx4 %0, %1, off sc0 sc1" :: "v"(p), "v"(vv));
}
__device__ __forceinline__ int ld_flag(const int* p) {
    int v;
    asm volatile("global_load_dword %0, %1, off sc0 sc1\n\ts_waitcnt vmcnt(0)"
                 : "=v"(v) : "v"(p) : "memory");
    return v;
}
__device__ __forceinline__ void st_flag(int* p, int v) {
    asm volatile("global_store_dword %0, %1, off sc0 sc1" :: "v"(p), "v"(v));
}
__device__ __forceinline__ void poll3(const int* p0, int t0,
                                      const int* p1, int t1,
                                      const int* p2, int t2) {
    for (;;) {
        bool ok = true;
        if (p0) ok = ok && (ld_flag(p0) >= t0);
        if (p1) ok = ok && (ld_flag(p1) >= t1);
        if (p2) ok = ok && (ld_flag(p2) >= t2);
        if (__all(ok)) break;
        __builtin_amdgcn_s_sleep(2);
    }
}
#define WAITV(n) asm volatile("s_waitcnt vmcnt(" #n ")" ::: "memory")
#define LGKM0    asm volatile("s_waitcnt lgkmcnt(0)" ::: "memory")
#define SCHEDB   __builtin_amdgcn_sched_barrier(0)

__device__ __forceinline__ void l2_acquire_inv() {
    __builtin_amdgcn_fence(__ATOMIC_ACQUIRE, "agent");
}

// qp MUST be a literal at each call site (compile-time register indices)
#define ISSUE8(buf, base, qp) do {                                          \
    _Pragma("unroll")                                                       \
    for (int m_ = 0; m_ < 4; ++m_)                                          \
        _Pragma("unroll")                                                   \
        for (int dq_ = 0; dq_ < 2; ++dq_)                                   \
            ld_ca(buf[m_*2+dq_], (base) + m_*16*H_SZ + (2*(qp)+dq_)*32);    \
} while (0)

#define COMP_L0(buf, qp) do {                                               \
    _Pragma("unroll")                                                       \
    for (int m_ = 0; m_ < 4; ++m_)                                          \
        _Pragma("unroll")                                                   \
        for (int dq_ = 0; dq_ < 2; ++dq_)                                   \
            _Pragma("unroll")                                               \
            for (int g_ = 0; g_ < 4; ++g_)                                  \
                acc[m_][g_] = mfma16(buf[m_*2+dq_], Wh[g_][2*(qp)+dq_],     \
                                     acc[m_][g_]);                          \
} while (0)

#define COMP_L1(buf, qp) do {                                               \
    _Pragma("unroll")                                                       \
    for (int m_ = 0; m_ < 4; ++m_)                                          \
        _Pragma("unroll")                                                   \
        for (int dq_ = 0; dq_ < 2; ++dq_)                                   \
            _Pragma("unroll")                                               \
            for (int nt_ = 0; nt_ < 2; ++nt_)                               \
                acc[m_][nt_] = mfma16(buf[m_*2+dq_], Wt[nt_][2*(qp)+dq_],   \
                                      acc[m_][nt_]);                        \
} while (0)

__global__ __launch_bounds__(256) void cvt_kernel(const float* __restrict__ s,
                                                  u16* __restrict__ d, int n)
{
    int i = (blockIdx.x * 256 + threadIdx.x) * 4;
    if (i >= n) return;
    float4 v = *(const float4*)(s + i);
    ushort4 o;
    o.x = f2bf(v.x); o.y = f2bf(v.y); o.z = f2bf(v.z); o.w = f2bf(v.w);
    *(ushort4*)(d + i) = o;
}

__global__ __launch_bounds__(256, 1) void persist_kernel(
    const u16* __restrict__ xb,
    const u16* __restrict__ Wih0c, const u16* __restrict__ Whh0c,
    const u16* __restrict__ Wih1c, const u16* __restrict__ Whh1c,
    const u16* __restrict__ Wfcc,
    const float* __restrict__ bih0, const float* __restrict__ bhh0,
    const float* __restrict__ bih1, const float* __restrict__ bhh1,
    const float* __restrict__ bfc,
    u16* __restrict__ h0b, u16* __restrict__ h1b,
    int* __restrict__ flagL0, int* __restrict__ flagL1, int* __restrict__ flagFC,
    float* __restrict__ out)
{
    __shared__ union { f32x4 v[4096]; float lg[16][132]; } red;   // 64KB
    __shared__ u16 trbuf[4][384];                                 // 3KB

    const int bid = blockIdx.x, tid = threadIdx.x;
    const int wave = tid >> 6, lane = tid & 63;
    const int l16 = lane & 15, kgi = lane >> 4, kg8 = kgi * 8;

    // ======================= LAYER 0 : blocks 0..63 =======================
    if (bid < 64) {
        const int j0 = bid * 16, jj = j0 + l16;
        // ---- weights -> registers (wave w owns K-quarter w) ----
        u16x8 Wh[4][8]; u16x8 Wx[4];
        #pragma unroll
        for (int g = 0; g < 4; ++g) {
            const size_t gr = (size_t)(g * H_SZ + jj);
            #pragma unroll
            for (int q = 0; q < 8; ++q)
                Wh[g][q] = *(const u16x8*)(Whh0c + gr * H_SZ + wave * 256 + q * 32 + kg8);
            Wx[g] = *(const u16x8*)(Wih0c + gr * V_SZ + wave * 32 + kg8);
        }
        const float bii = bih0[jj]            + bhh0[jj];
        const float bif = bih0[H_SZ + jj]     + bhh0[H_SZ + jj];
        const float big = bih0[2 * H_SZ + jj] + bhh0[2 * H_SZ + jj];
        const float bio = bih0[3 * H_SZ + jj] + bhh0[3 * H_SZ + jj];

        const size_t aoff = (size_t)l16 * H_SZ + wave * 256 + kg8;
        float creg[4] = {0.f, 0.f, 0.f, 0.f};

        for (int t = 0; t < S_LEN; ++t) {
            // x loads (own K-slice of V=128) issued before the wait
            i32x4 xa[4];
            #pragma unroll
            for (int m = 0; m < 4; ++m)
                ld_ca(xa[m], xb + (size_t)(m * 16 + l16) * (S_LEN * V_SZ)
                              + (size_t)t * V_SZ + wave * 32 + kg8);
            poll3((t >= 1)    ? flagL0 + lane * FSTR        : nullptr, t,
                  (t >= RING) ? flagL1 + lane * FSTR        : nullptr, t - (RING - 1),
                  (t >= RING) ? flagL1 + (64 + lane) * FSTR : nullptr, t - (RING - 1));
            if (t >= INVP && (t % INVP) == 0) l2_acquire_inv();
            WAITV(0); SCHEDB;                 // xa valid (poll may be a no-op)

            f32x4 acc[4][4];
            #pragma unroll
            for (int m = 0; m < 4; ++m)
                #pragma unroll
                for (int g = 0; g < 4; ++g) acc[m][g] = (f32x4){0.f, 0.f, 0.f, 0.f};

            const u16* aB = h0b + (size_t)((t - 1) & (RING - 1)) * SLOT + aoff;
            i32x4 A0[8], A1[8];
            ISSUE8(A0, aB, 0); ISSUE8(A1, aB, 1);
            SCHEDB;
            // x-pass while h-loads are in flight
            #pragma unroll
            for (int m = 0; m < 4; ++m)
                #pragma unroll
                for (int g = 0; g < 4; ++g)
                    acc[m][g] = mfma16(xa[m], Wx[g], acc[m][g]);
            WAITV(8); SCHEDB; COMP_L0(A0, 0); ISSUE8(A0, aB, 2);
            WAITV(8); SCHEDB; COMP_L0(A1, 1); ISSUE8(A1, aB, 3);
            WAITV(8); SCHEDB; COMP_L0(A0, 2);
            WAITV(0); SCHEDB; COMP_L0(A1, 3);

            // ---- cross-wave K-reduce (LDS, stride-16B conflict-free) ----
            #pragma unroll
            for (int m = 0; m < 4; ++m)
                #pragma unroll
                for (int g = 0; g < 4; ++g)
                    red.v[(wave * 16 + m * 4 + g) * 64 + lane] = acc[m][g];
            __syncthreads();
            f32x4 s[4];
            #pragma unroll
            for (int g = 0; g < 4; ++g) {
                s[g] = red.v[(wave * 4 + g) * 64 + lane];
                #pragma unroll
                for (int w = 1; w < 4; ++w) {
                    f32x4 p = red.v[(w * 16 + wave * 4 + g) * 64 + lane];
                    s[g][0] += p[0]; s[g][1] += p[1]; s[g][2] += p[2]; s[g][3] += p[3];
                }
            }

            // fused LSTM update (wave owns M-tile == wave) + transpose-store
            u16* hout = h0b + (size_t)(t & (RING - 1)) * SLOT;
            #pragma unroll
            for (int r = 0; r < 4; ++r) {
                const float ip = s[0][r] + bii;
                const float fp = s[1][r] + bif;
                const float gp = s[2][r] + big;
                const float op = s[3][r] + bio;
                const float iv = 1.f / (1.f + expf(-ip));
                const float fv = 1.f / (1.f + expf(-fp));
                const float gv = tanhf(gp);
                const float ov = 1.f / (1.f + expf(-op));
                const float cv = fv * creg[r] + iv * gv;
                creg[r] = cv;
                trbuf[wave][(kgi * 4 + r) * 24 + l16] = f2bf(ov * tanhf(cv));
            }
            LGKM0; SCHEDB;
            if (lane < 32) {
                int m = lane >> 1, jb = lane & 1;
                u16x8 v = *(const u16x8*)&trbuf[wave][m * 24 + jb * 8];
                st_coh16(hout + (size_t)(wave * 16 + m) * H_SZ + j0 + jb * 8, v);
            }
            WAITV(0);
            __syncthreads();
            if (tid == 0) st_flag(flagL0 + bid * FSTR, t + 1);
        }
        return;
    }

    // ======================= LAYER 1 : blocks 64..191 =======================
    if (bid < 192) {
        const int lb = bid - 64, j0 = lb * 8, jj2 = j0 + (l16 & 7);
        // waves 0/1: Wih1 (operand h0[t]), K-half (wave&1)*512
        // waves 2/3: Whh1 (operand h1[t-1]), K-half (wave&1)*512
        const u16* Wsrc = (wave < 2) ? Wih1c : Whh1c;
        const int kbase = (wave & 1) * 512;
        u16x8 Wt[2][16];
        #pragma unroll
        for (int nt = 0; nt < 2; ++nt) {
            const int rl = nt * 16 + l16;
            const size_t gr = (size_t)((rl >> 3) * H_SZ + j0 + (rl & 7));
            #pragma unroll
            for (int q = 0; q < 16; ++q)
                Wt[nt][q] = *(const u16x8*)(Wsrc + gr * H_SZ + kbase + q * 32 + kg8);
        }
        const float bii = bih1[jj2]            + bhh1[jj2];
        const float bif = bih1[H_SZ + jj2]     + bhh1[H_SZ + jj2];
        const float big = bih1[2 * H_SZ + jj2] + bhh1[2 * H_SZ + jj2];
        const float bio = bih1[3 * H_SZ + jj2] + bhh1[3 * H_SZ + jj2];
        const bool lo = (l16 < 8);

        const size_t aoff = (size_t)l16 * H_SZ + kbase + kg8;
        float creg[4] = {0.f, 0.f, 0.f, 0.f};

        for (int t = 0; t < S_LEN; ++t) {
            if (wave < 2)      // need h0[t]; WAR: FC consumed h1 slot t-32
                poll3(flagL0 + lane * FSTR, t + 1,
                      (t >= RING) ? flagFC + (lane & 3) * FSTR : nullptr, t - (RING - 1),
                      nullptr, 0);
            else               // need h1[t-1] (all 128 L1 blocks); WAR: FC
                poll3((t >= 1)    ? flagL1 + lane * FSTR        : nullptr, t,
                      (t >= 1)    ? flagL1 + (64 + lane) * FSTR : nullptr, t,
                      (t >= RING) ? flagFC + (lane & 3) * FSTR  : nullptr, t - (RING - 1));
            if (t >= INVP && (t % INVP) == 0) l2_acquire_inv();

            const u16* aB = ((wave < 2)
                ? h0b + (size_t)(t & (RING - 1)) * SLOT
                : h1b + (size_t)((t - 1) & (RING - 1)) * SLOT) + aoff;

            f32x4 acc[4][2];
            #pragma unroll
            for (int m = 0; m < 4; ++m)
                #pragma unroll
                for (int nt = 0; nt < 2; ++nt) acc[m][nt] = (f32x4){0.f, 0.f, 0.f, 0.f};

            i32x4 A0[8], A1[8];
            ISSUE8(A0, aB, 0); ISSUE8(A1, aB, 1);
            WAITV(8); SCHEDB; COMP_L1(A0, 0); ISSUE8(A0, aB, 2);
            WAITV(8); SCHEDB; COMP_L1(A1, 1); ISSUE8(A1, aB, 3);
            WAITV(8); SCHEDB; COMP_L1(A0, 2); ISSUE8(A0, aB, 4);
            WAITV(8); SCHEDB; COMP_L1(A1, 3); ISSUE8(A1, aB, 5);
            WAITV(8); SCHEDB; COMP_L1(A0, 4); ISSUE8(A0, aB, 6);
            WAITV(8); SCHEDB; COMP_L1(A1, 5); ISSUE8(A1, aB, 7);
            WAITV(8); SCHEDB; COMP_L1(A0, 6);
            WAITV(0); SCHEDB; COMP_L1(A1, 7);

            // ---- cross-wave reduce ----
            #pragma unroll
            for (int m = 0; m < 4; ++m)
                #pragma unroll
                for (int nt = 0; nt < 2; ++nt)
                    red.v[(wave * 16 + m * 2 + nt) * 64 + lane] = acc[m][nt];
            __syncthreads();
            f32x4 s[2];
            #pragma unroll
            for (int nt = 0; nt < 2; ++nt) {
                s[nt] = red.v[(wave * 2 + nt) * 64 + lane];
                #pragma unroll
                for (int w = 1; w < 4; ++w) {
                    f32x4 p = red.v[(w * 16 + wave * 2 + nt) * 64 + lane];
                    s[nt][0] += p[0]; s[nt][1] += p[1]; s[nt][2] += p[2]; s[nt][3] += p[3];
                }
            }

            // epilogue: tile0=(i|f), tile1=(g|o); pair exchange; transpose-store
            #pragma unroll
            for (int r = 0; r < 4; ++r) {
                const float s0 = s[0][r];
                const float s1 = s[1][r];
                const float q0 = __shfl_xor(s0, 8);
                const float q1 = __shfl_xor(s1, 8);
                const float ip = (lo ? s0 : q0) + bii;
                const float fp = (lo ? q0 : s0) + bif;
                const float gp = (lo ? s1 : q1) + big;
                const float op = (lo ? q1 : s1) + bio;
                const float iv = 1.f / (1.f + expf(-ip));
                const float fv = 1.f / (1.f + expf(-fp));
                const float gv = tanhf(gp);
                const float ov = 1.f / (1.f + expf(-op));
                const float cv = fv * creg[r] + iv * gv;
                creg[r] = cv;
                if (lo) trbuf[wave][(kgi * 4 + r) * 24 + (l16 & 7)] = f2bf(ov * tanhf(cv));
            }
            LGKM0; SCHEDB;
            if (lane < 16) {
                u16x8 v = *(const u16x8*)&trbuf[wave][lane * 24];
                st_coh16(h1b + (size_t)(t & (RING - 1)) * SLOT
                         + (size_t)(wave * 16 + lane) * H_SZ + j0, v);
            }
            WAITV(0);
            __syncthreads();
            if (tid == 0) st_flag(flagL1 + lb * FSTR, t + 1);
        }
        return;
    }

    // ======================= FC : blocks 192..195 =======================
    {
        const int fb = bid - 192, m0 = fb * 16;
        const u16* wp[2];
        #pragma unroll
        for (int nt = 0; nt < 2; ++nt)
            wp[nt] = Wfcc + (size_t)(wave * 32 + nt * 16 + l16) * H_SZ + kg8;

        for (int t = 0; t < S_LEN; ++t) {
            poll3(flagL1 + lane * FSTR, t + 1,
                  flagL1 + (64 + lane) * FSTR, t + 1, nullptr, 0);
            if (t >= INVP && (t % INVP) == 0) l2_acquire_inv();

            const u16* aB = h1b + (size_t)(t & (RING - 1)) * SLOT
                          + (size_t)(m0 + l16) * H_SZ + kg8;
            f32x4 acc[2][2] = {};
            i32x4 buf[8];
            #pragma unroll
            for (int c = 0; c < 4; ++c) {
                #pragma unroll
                for (int q = 0; q < 8; ++q) ld_ca(buf[q], aB + c * 256 + q * 32);
                WAITV(0); SCHEDB;
                #pragma unroll
                for (int q = 0; q < 8; ++q) {
                    #pragma unroll
                    for (int nt = 0; nt < 2; ++nt)
                        acc[nt][q & 1] = mfma16(buf[q],
                            *(const u16x8*)(wp[nt] + (c * 8 + q) * 32), acc[nt][q & 1]);
                }
            }
            #pragma unroll
            for (int nt = 0; nt < 2; ++nt)
                #pragma unroll
                for (int r = 0; r < 4; ++r) {
                    const int m = kgi * 4 + r, n = wave * 32 + nt * 16 + l16;
                    red.lg[m][n] = acc[nt][0][r] + acc[nt][1][r] + bfc[n];
                }
            __syncthreads();
            const int row = tid >> 4, sub = tid & 15;
            float vals[8]; float mx = -1e30f;
            #pragma unroll
            for (int q = 0; q < 8; ++q) { vals[q] = red.lg[row][sub * 8 + q]; mx = fmaxf(mx, vals[q]); }
            #pragma unroll
            for (int o = 1; o < 16; o <<= 1) mx = fmaxf(mx, __shfl_xor(mx, o));
            float se = 0.f;
            #pragma unroll
            for (int q = 0; q < 8; ++q) se += expf(vals[q] - mx);
            #pragma unroll
            for (int o = 1; o < 16; o <<= 1) se += __shfl_xor(se, o);
            const float ls = mx + logf(se);
            float* op = out + (size_t)(m0 + row) * (S_LEN * V_SZ) + (size_t)t * V_SZ + sub * 8;
            #pragma unroll
            for (int q = 0; q < 8; ++q) op[q] = vals[q] - ls;

            __syncthreads();
            if (tid == 0) st_flag(flagFC + fb * FSTR, t + 1);
        }
    }
}

// =============================== launcher ==================================
extern "C" void kernel_launch(void* const* d_in, const int* in_sizes, int n_in,
                              void* d_out, int out_size, void* d_ws, size_t ws_size,
                              hipStream_t stream)
{
    const float* x    = (const float*)d_in[0];
    const float* Wih0 = (const float*)d_in[1];
    const float* Whh0 = (const float*)d_in[2];
    const float* bih0 = (const float*)d_in[3];
    const float* bhh0 = (const float*)d_in[4];
    const float* Wih1 = (const float*)d_in[5];
    const float* Whh1 = (const float*)d_in[6];
    const float* bih1 = (const float*)d_in[7];
    const float* bhh1 = (const float*)d_in[8];
    const float* Wfc  = (const float*)d_in[9];
    const float* bfc  = (const float*)d_in[10];
    float* out = (float*)d_out;

    u16* wih0 = (u16*)d_ws;
    u16* whh0 = wih0 + (size_t)4096 * 128;
    u16* wih1 = whh0 + (size_t)4096 * 1024;
    u16* whh1 = wih1 + (size_t)4096 * 1024;
    u16* wfc  = whh1 + (size_t)4096 * 1024;
    u16* xbuf = wfc  + (size_t)128 * 1024;
    u16* h0b  = xbuf + (size_t)B_SZ * S_LEN * V_SZ;
    u16* h1b  = h0b + (size_t)RING * SLOT;
    int* flags  = (int*)(h1b + (size_t)RING * SLOT);
    int* flagL0 = flags;
    int* flagL1 = flagL0 + 64 * FSTR;
    int* flagFC = flagL1 + 128 * FSTR;

    auto cvt = [&](const float* s, u16* d, int n) {
        cvt_kernel<<<(n / 4 + 255) / 256, 256, 0, stream>>>(s, d, n);
    };
    cvt(Wih0, wih0, 4096 * 128);
    cvt(Whh0, whh0, 4096 * 1024);
    cvt(Wih1, wih1, 4096 * 1024);
    cvt(Whh1, whh1, 4096 * 1024);
    cvt(Wfc,  wfc,  128 * 1024);
    cvt(x,    xbuf, B_SZ * S_LEN * V_SZ);
    hipMemsetAsync(h0b + (size_t)(RING - 1) * SLOT, 0, (size_t)BH * sizeof(u16), stream);
    hipMemsetAsync(h1b + (size_t)(RING - 1) * SLOT, 0, (size_t)BH * sizeof(u16), stream);
    hipMemsetAsync(flags, 0, (size_t)196 * FSTR * sizeof(int), stream);

    persist_kernel<<<196, 256, 0, stream>>>(
        xbuf, wih0, whh0, wih1, whh1, wfc,
        bih0, bhh0, bih1, bhh1, bfc,
        h0b, h1b, flagL0, flagL1, flagFC, out);
}

// Round 13
// 6335.378 us; speedup vs baseline: 1.1658x; 1.0039x over previous
//
#include <hip/hip_runtime.h>
#include <hip/hip_bf16.h>
#include <math.h>

// ---------------------------------------------------------------------------
// Round 13: r11 structure (PASSED, 6.36ms) + minimal delta:
//  (1) PINNED register weights via asm-volatile preload (ld_w) — COMP regions
//      contain zero compiler memory ops, so compiler waitcnts can't drain the
//      counted h-pipeline (r11 postmortem: VGPR=164 proved weight re-fetch).
//  (2) h loads via sc0sc1 bypass (r5-proven) — removes the stale-L2 hazard
//      that r11's cached loads would acquire once weights stop churning L2.
//  Everything else verbatim from r11: rolling 2-buffer vmcnt pipeline, poll3
//  per-wave flag waits, cross-wave K-reduce, epilogues, FC block.
// Blocks: [0,64) L0 16-col, [64,192) L1 8-col, [192,196) FC. 256 thr.
// ---------------------------------------------------------------------------

#define S_LEN 512
#define B_SZ  64
#define V_SZ  128
#define H_SZ  1024
#define BH    65536
#define RING  32
#define SLOT  66560          // BH + 1024 u16 pad
#define FSTR  16

typedef unsigned short u16;
typedef unsigned short u16x8 __attribute__((ext_vector_type(8)));
typedef __bf16         bf16x8 __attribute__((ext_vector_type(8)));
typedef float          f32x4  __attribute__((ext_vector_type(4)));
typedef int            i32x4  __attribute__((ext_vector_type(4)));

__device__ __forceinline__ u16 f2bf(float f) {
    unsigned int u = __float_as_uint(f);
    u += 0x7fffu + ((u >> 16) & 1u);
    return (u16)(u >> 16);
}
__device__ __forceinline__ f32x4 mfma16(u16x8 a, u16x8 b, f32x4 c) {
    return __builtin_amdgcn_mfma_f32_16x16x32_bf16(
        __builtin_bit_cast(bf16x8, a), __builtin_bit_cast(bf16x8, b), c, 0, 0, 0);
}
__device__ __forceinline__ f32x4 mfma16(i32x4 a, u16x8 b, f32x4 c) {
    return __builtin_amdgcn_mfma_f32_16x16x32_bf16(
        __builtin_bit_cast(bf16x8, a), __builtin_bit_cast(bf16x8, b), c, 0, 0, 0);
}

// coherent (bypass) load for h-state — r5-proven correct
__device__ __forceinline__ void ld_cv(i32x4& d, const u16* p) {
    asm volatile("global_load_dwordx4 %0, %1, off sc0 sc1" : "=v"(d) : "v"(p));
}
// cached load for immutable x
__device__ __forceinline__ void ld_ca(i32x4& d, const u16* p) {
    asm volatile("global_load_dwordx4 %0, %1, off" : "=v"(d) : "v"(p));
}
// PINNED weight load: asm volatile => not sinkable/rematerializable
__device__ __forceinline__ void ld_w(u16x8& d, const u16* p) {
    asm volatile("global_load_dwordx4 %0, %1, off" : "=v"(d) : "v"(p));
}
__device__ __forceinline__ void st_coh16(u16* p, u16x8 v) {
    i32x4 vv = __builtin_bit_cast(i32x4, v);
    asm volatile("global_store_dwordx4 %0, %1, off sc0 sc1" :: "v"(p), "v"(vv));
}
__device__ __forceinline__ int ld_flag(const int* p) {
    int v;
    asm volatile("global_load_dword %0, %1, off sc0 sc1\n\ts_waitcnt vmcnt(0)"
                 : "=v"(v) : "v"(p) : "memory");
    return v;
}
__device__ __forceinline__ void st_flag(int* p, int v) {
    asm volatile("global_store_dword %0, %1, off sc0 sc1" :: "v"(p), "v"(v));
}
__device__ __forceinline__ void poll3(const int* p0, int t0,
                                      const int* p1, int t1,
                                      const int* p2, int t2) {
    for (;;) {
        bool ok = true;
        if (p0) ok = ok && (ld_flag(p0) >= t0);
        if (p1) ok = ok && (ld_flag(p1) >= t1);
        if (p2) ok = ok && (ld_flag(p2) >= t2);
        if (__all(ok)) break;
        __builtin_amdgcn_s_sleep(2);
    }
}
#define WAITV(n) asm volatile("s_waitcnt vmcnt(" #n ")" ::: "memory")
#define LGKM0    asm volatile("s_waitcnt lgkmcnt(0)" ::: "memory")
#define SCHEDB   __builtin_amdgcn_sched_barrier(0)

// qp is a literal at each call site
#define ISSUE8(buf, base, qp) do {                                          \
    _Pragma("unroll")                                                       \
    for (int m_ = 0; m_ < 4; ++m_)                                          \
        _Pragma("unroll")                                                   \
        for (int dq_ = 0; dq_ < 2; ++dq_)                                   \
            ld_cv(buf[m_*2+dq_], (base) + m_*16*H_SZ + (2*(qp)+dq_)*32);    \
} while (0)

#define COMP_L0(buf, qp) do {                                               \
    _Pragma("unroll")                                                       \
    for (int m_ = 0; m_ < 4; ++m_)                                          \
        _Pragma("unroll")                                                   \
        for (int dq_ = 0; dq_ < 2; ++dq_)                                   \
            _Pragma("unroll")                                               \
            for (int g_ = 0; g_ < 4; ++g_)                                  \
                acc[m_][g_] = mfma16(buf[m_*2+dq_], Wh[g_][2*(qp)+dq_],     \
                                     acc[m_][g_]);                          \
} while (0)

#define COMP_L1(buf, qp) do {                                               \
    _Pragma("unroll")                                                       \
    for (int m_ = 0; m_ < 4; ++m_)                                          \
        _Pragma("unroll")                                                   \
        for (int dq_ = 0; dq_ < 2; ++dq_)                                   \
            _Pragma("unroll")                                               \
            for (int nt_ = 0; nt_ < 2; ++nt_)                               \
                acc[m_][nt_] = mfma16(buf[m_*2+dq_], Wt[nt_][2*(qp)+dq_],   \
                                      acc[m_][nt_]);                        \
} while (0)

__global__ __launch_bounds__(256) void cvt_kernel(const float* __restrict__ s,
                                                  u16* __restrict__ d, int n)
{
    int i = (blockIdx.x * 256 + threadIdx.x) * 4;
    if (i >= n) return;
    float4 v = *(const float4*)(s + i);
    ushort4 o;
    o.x = f2bf(v.x); o.y = f2bf(v.y); o.z = f2bf(v.z); o.w = f2bf(v.w);
    *(ushort4*)(d + i) = o;
}

__global__ __launch_bounds__(256, 1) void persist_kernel(
    const u16* __restrict__ xb,
    const u16* __restrict__ Wih0c, const u16* __restrict__ Whh0c,
    const u16* __restrict__ Wih1c, const u16* __restrict__ Whh1c,
    const u16* __restrict__ Wfcc,
    const float* __restrict__ bih0, const float* __restrict__ bhh0,
    const float* __restrict__ bih1, const float* __restrict__ bhh1,
    const float* __restrict__ bfc,
    u16* __restrict__ h0b, u16* __restrict__ h1b,
    int* __restrict__ flagL0, int* __restrict__ flagL1, int* __restrict__ flagFC,
    float* __restrict__ out)
{
    __shared__ union { f32x4 v[4096]; float lg[16][132]; } red;   // 64KB
    __shared__ u16 trbuf[4][384];

    const int bid = blockIdx.x, tid = threadIdx.x;
    const int wave = tid >> 6, lane = tid & 63;
    const int l16 = lane & 15, kgi = lane >> 4, kg8 = kgi * 8;

    // ======================= LAYER 0 : blocks 0..63 =======================
    if (bid < 64) {
        const int j0 = bid * 16, jj = j0 + l16;
        // ---- PINNED weights: wave w owns K-quarter w ----
        u16x8 Wh[4][8]; u16x8 Wx[4];
        #pragma unroll
        for (int g = 0; g < 4; ++g) {
            const size_t gr = (size_t)(g * H_SZ + jj);
            #pragma unroll
            for (int q = 0; q < 8; ++q)
                ld_w(Wh[g][q], Whh0c + gr * H_SZ + wave * 256 + q * 32 + kg8);
            ld_w(Wx[g], Wih0c + gr * V_SZ + wave * 32 + kg8);
        }
        WAITV(0);
        const float bii = bih0[jj]            + bhh0[jj];
        const float bif = bih0[H_SZ + jj]     + bhh0[H_SZ + jj];
        const float big = bih0[2 * H_SZ + jj] + bhh0[2 * H_SZ + jj];
        const float bio = bih0[3 * H_SZ + jj] + bhh0[3 * H_SZ + jj];

        const size_t aoff = (size_t)l16 * H_SZ + wave * 256 + kg8;
        float creg[4] = {0.f, 0.f, 0.f, 0.f};

        for (int t = 0; t < S_LEN; ++t) {
            i32x4 xa[4];
            #pragma unroll
            for (int m = 0; m < 4; ++m)
                ld_ca(xa[m], xb + (size_t)(m * 16 + l16) * (S_LEN * V_SZ)
                              + (size_t)t * V_SZ + wave * 32 + kg8);
            poll3((t >= 1)    ? flagL0 + lane * FSTR        : nullptr, t,
                  (t >= RING) ? flagL1 + lane * FSTR        : nullptr, t - (RING - 1),
                  (t >= RING) ? flagL1 + (64 + lane) * FSTR : nullptr, t - (RING - 1));
            WAITV(0); SCHEDB;                 // xa valid for all lanes

            f32x4 acc[4][4];
            #pragma unroll
            for (int m = 0; m < 4; ++m)
                #pragma unroll
                for (int g = 0; g < 4; ++g) acc[m][g] = (f32x4){0.f, 0.f, 0.f, 0.f};

            const u16* aB = h0b + (size_t)((t - 1) & (RING - 1)) * SLOT + aoff;
            i32x4 A0[8], A1[8];
            ISSUE8(A0, aB, 0); ISSUE8(A1, aB, 1);
            SCHEDB;
            // x-pass while h-loads are in flight (weights in regs, no mem ops)
            #pragma unroll
            for (int m = 0; m < 4; ++m)
                #pragma unroll
                for (int g = 0; g < 4; ++g)
                    acc[m][g] = mfma16(xa[m], Wx[g], acc[m][g]);
            WAITV(8); SCHEDB; COMP_L0(A0, 0); ISSUE8(A0, aB, 2);
            WAITV(8); SCHEDB; COMP_L0(A1, 1); ISSUE8(A1, aB, 3);
            WAITV(8); SCHEDB; COMP_L0(A0, 2);
            WAITV(0); SCHEDB; COMP_L0(A1, 3);

            // ---- cross-wave K-reduce (LDS, conflict-free) ----
            #pragma unroll
            for (int m = 0; m < 4; ++m)
                #pragma unroll
                for (int g = 0; g < 4; ++g)
                    red.v[(wave * 16 + m * 4 + g) * 64 + lane] = acc[m][g];
            __syncthreads();
            f32x4 s[4];
            #pragma unroll
            for (int g = 0; g < 4; ++g) {
                s[g] = red.v[(wave * 4 + g) * 64 + lane];
                #pragma unroll
                for (int w = 1; w < 4; ++w) {
                    f32x4 p = red.v[(w * 16 + wave * 4 + g) * 64 + lane];
                    s[g][0] += p[0]; s[g][1] += p[1]; s[g][2] += p[2]; s[g][3] += p[3];
                }
            }

            u16* hout = h0b + (size_t)(t & (RING - 1)) * SLOT;
            #pragma unroll
            for (int r = 0; r < 4; ++r) {
                const float ip = s[0][r] + bii;
                const float fp = s[1][r] + bif;
                const float gp = s[2][r] + big;
                const float op = s[3][r] + bio;
                const float iv = 1.f / (1.f + expf(-ip));
                const float fv = 1.f / (1.f + expf(-fp));
                const float gv = tanhf(gp);
                const float ov = 1.f / (1.f + expf(-op));
                const float cv = fv * creg[r] + iv * gv;
                creg[r] = cv;
                trbuf[wave][(kgi * 4 + r) * 24 + l16] = f2bf(ov * tanhf(cv));
            }
            LGKM0; SCHEDB;
            if (lane < 32) {
                int m = lane >> 1, jb = lane & 1;
                u16x8 v = *(const u16x8*)&trbuf[wave][m * 24 + jb * 8];
                st_coh16(hout + (size_t)(wave * 16 + m) * H_SZ + j0 + jb * 8, v);
            }
            WAITV(0);
            __syncthreads();
            if (tid == 0) st_flag(flagL0 + bid * FSTR, t + 1);
        }
        return;
    }

    // ======================= LAYER 1 : blocks 64..191 =======================
    if (bid < 192) {
        const int lb = bid - 64, j0 = lb * 8, jj2 = j0 + (l16 & 7);
        // waves 0/1: Wih1 (operand h0[t]); waves 2/3: Whh1 (operand h1[t-1]);
        // K-half (wave&1)*512. PINNED.
        const u16* Wsrc = (wave < 2) ? Wih1c : Whh1c;
        const int kbase = (wave & 1) * 512;
        u16x8 Wt[2][16];
        #pragma unroll
        for (int nt = 0; nt < 2; ++nt) {
            const int rl = nt * 16 + l16;
            const size_t gr = (size_t)((rl >> 3) * H_SZ + j0 + (rl & 7));
            #pragma unroll
            for (int q = 0; q < 16; ++q)
                ld_w(Wt[nt][q], Wsrc + gr * H_SZ + kbase + q * 32 + kg8);
        }
        WAITV(0);
        const float bii = bih1[jj2]            + bhh1[jj2];
        const float bif = bih1[H_SZ + jj2]     + bhh1[H_SZ + jj2];
        const float big = bih1[2 * H_SZ + jj2] + bhh1[2 * H_SZ + jj2];
        const float bio = bih1[3 * H_SZ + jj2] + bhh1[3 * H_SZ + jj2];
        const bool lo = (l16 < 8);

        const size_t aoff = (size_t)l16 * H_SZ + kbase + kg8;
        float creg[4] = {0.f, 0.f, 0.f, 0.f};

        for (int t = 0; t < S_LEN; ++t) {
            if (wave < 2)
                poll3(flagL0 + lane * FSTR, t + 1,
                      (t >= RING) ? flagFC + (lane & 3) * FSTR : nullptr, t - (RING - 1),
                      nullptr, 0);
            else
                poll3((t >= 1)    ? flagL1 + lane * FSTR        : nullptr, t,
                      (t >= 1)    ? flagL1 + (64 + lane) * FSTR : nullptr, t,
                      (t >= RING) ? flagFC + (lane & 3) * FSTR  : nullptr, t - (RING - 1));

            const u16* aB = ((wave < 2)
                ? h0b + (size_t)(t & (RING - 1)) * SLOT
                : h1b + (size_t)((t - 1) & (RING - 1)) * SLOT) + aoff;

            f32x4 acc[4][2];
            #pragma unroll
            for (int m = 0; m < 4; ++m)
                #pragma unroll
                for (int nt = 0; nt < 2; ++nt) acc[m][nt] = (f32x4){0.f, 0.f, 0.f, 0.f};

            i32x4 A0[8], A1[8];
            ISSUE8(A0, aB, 0); ISSUE8(A1, aB, 1);
            SCHEDB;
            WAITV(8); SCHEDB; COMP_L1(A0, 0); ISSUE8(A0, aB, 2);
            WAITV(8); SCHEDB; COMP_L1(A1, 1); ISSUE8(A1, aB, 3);
            WAITV(8); SCHEDB; COMP_L1(A0, 2); ISSUE8(A0, aB, 4);
            WAITV(8); SCHEDB; COMP_L1(A1, 3); ISSUE8(A1, aB, 5);
            WAITV(8); SCHEDB; COMP_L1(A0, 4); ISSUE8(A0, aB, 6);
            WAITV(8); SCHEDB; COMP_L1(A1, 5); ISSUE8(A1, aB, 7);
            WAITV(8); SCHEDB; COMP_L1(A0, 6);
            WAITV(0); SCHEDB; COMP_L1(A1, 7);

            // ---- cross-wave reduce ----
            #pragma unroll
            for (int m = 0; m < 4; ++m)
                #pragma unroll
                for (int nt = 0; nt < 2; ++nt)
                    red.v[(wave * 16 + m * 2 + nt) * 64 + lane] = acc[m][nt];
            __syncthreads();
            f32x4 s[2];
            #pragma unroll
            for (int nt = 0; nt < 2; ++nt) {
                s[nt] = red.v[(wave * 2 + nt) * 64 + lane];
                #pragma unroll
                for (int w = 1; w < 4; ++w) {
                    f32x4 p = red.v[(w * 16 + wave * 2 + nt) * 64 + lane];
                    s[nt][0] += p[0]; s[nt][1] += p[1]; s[nt][2] += p[2]; s[nt][3] += p[3];
                }
            }

            #pragma unroll
            for (int r = 0; r < 4; ++r) {
                const float s0 = s[0][r];
                const float s1 = s[1][r];
                const float q0 = __shfl_xor(s0, 8);
                const float q1 = __shfl_xor(s1, 8);
                const float ip = (lo ? s0 : q0) + bii;
                const float fp = (lo ? q0 : s0) + bif;
                const float gp = (lo ? s1 : q1) + big;
                const float op = (lo ? q1 : s1) + bio;
                const float iv = 1.f / (1.f + expf(-ip));
                const float fv = 1.f / (1.f + expf(-fp));
                const float gv = tanhf(gp);
                const float ov = 1.f / (1.f + expf(-op));
                const float cv = fv * creg[r] + iv * gv;
                creg[r] = cv;
                if (lo) trbuf[wave][(kgi * 4 + r) * 24 + (l16 & 7)] = f2bf(ov * tanhf(cv));
            }
            LGKM0; SCHEDB;
            if (lane < 16) {
                u16x8 v = *(const u16x8*)&trbuf[wave][lane * 24];
                st_coh16(h1b + (size_t)(t & (RING - 1)) * SLOT
                         + (size_t)(wave * 16 + lane) * H_SZ + j0, v);
            }
            WAITV(0);
            __syncthreads();
            if (tid == 0) st_flag(flagL1 + lb * FSTR, t + 1);
        }
        return;
    }

    // ======================= FC : blocks 192..195 (verbatim r11) ============
    {
        const int fb = bid - 192, m0 = fb * 16;
        const u16* wp[2];
        #pragma unroll
        for (int nt = 0; nt < 2; ++nt)
            wp[nt] = Wfcc + (size_t)(wave * 32 + nt * 16 + l16) * H_SZ + kg8;

        for (int t = 0; t < S_LEN; ++t) {
            poll3(flagL1 + lane * FSTR, t + 1,
                  flagL1 + (64 + lane) * FSTR, t + 1, nullptr, 0);

            const u16* aB = h1b + (size_t)(t & (RING - 1)) * SLOT
                          + (size_t)(m0 + l16) * H_SZ + kg8;
            f32x4 acc[2][2] = {};
            i32x4 buf[8];
            #pragma unroll
            for (int c = 0; c < 4; ++c) {
                #pragma unroll
                for (int q = 0; q < 8; ++q) ld_cv(buf[q], aB + c * 256 + q * 32);
                WAITV(0); SCHEDB;
                #pragma unroll
                for (int q = 0; q < 8; ++q) {
                    #pragma unroll
                    for (int nt = 0; nt < 2; ++nt)
                        acc[nt][q & 1] = mfma16(buf[q],
                            *(const u16x8*)(wp[nt] + (c * 8 + q) * 32), acc[nt][q & 1]);
                }
            }
            #pragma unroll
            for (int nt = 0; nt < 2; ++nt)
                #pragma unroll
                for (int r = 0; r < 4; ++r) {
                    const int m = kgi * 4 + r, n = wave * 32 + nt * 16 + l16;
                    red.lg[m][n] = acc[nt][0][r] + acc[nt][1][r] + bfc[n];
                }
            __syncthreads();
            const int row = tid >> 4, sub = tid & 15;
            float vals[8]; float mx = -1e30f;
            #pragma unroll
            for (int q = 0; q < 8; ++q) { vals[q] = red.lg[row][sub * 8 + q]; mx = fmaxf(mx, vals[q]); }
            #pragma unroll
            for (int o = 1; o < 16; o <<= 1) mx = fmaxf(mx, __shfl_xor(mx, o));
            float se = 0.f;
            #pragma unroll
            for (int q = 0; q < 8; ++q) se += expf(vals[q] - mx);
            #pragma unroll
            for (int o = 1; o < 16; o <<= 1) se += __shfl_xor(se, o);
            const float ls = mx + logf(se);
            float* op = out + (size_t)(m0 + row) * (S_LEN * V_SZ) + (size_t)t * V_SZ + sub * 8;
            #pragma unroll
            for (int q = 0; q < 8; ++q) op[q] = vals[q] - ls;

            __syncthreads();
            if (tid == 0) st_flag(flagFC + fb * FSTR, t + 1);
        }
    }
}

// =============================== launcher ==================================
extern "C" void kernel_launch(void* const* d_in, const int* in_sizes, int n_in,
                              void* d_out, int out_size, void* d_ws, size_t ws_size,
                              hipStream_t stream)
{
    const float* x    = (const float*)d_in[0];
    const float* Wih0 = (const float*)d_in[1];
    const float* Whh0 = (const float*)d_in[2];
    const float* bih0 = (const float*)d_in[3];
    const float* bhh0 = (const float*)d_in[4];
    const float* Wih1 = (const float*)d_in[5];
    const float* Whh1 = (const float*)d_in[6];
    const float* bih1 = (const float*)d_in[7];
    const float* bhh1 = (const float*)d_in[8];
    const float* Wfc  = (const float*)d_in[9];
    const float* bfc  = (const float*)d_in[10];
    float* out = (float*)d_out;

    u16* wih0 = (u16*)d_ws;
    u16* whh0 = wih0 + (size_t)4096 * 128;
    u16* wih1 = whh0 + (size_t)4096 * 1024;
    u16* whh1 = wih1 + (size_t)4096 * 1024;
    u16* wfc  = whh1 + (size_t)4096 * 1024;
    u16* xbuf = wfc  + (size_t)128 * 1024;
    u16* h0b  = xbuf + (size_t)B_SZ * S_LEN * V_SZ;
    u16* h1b  = h0b + (size_t)RING * SLOT;
    int* flags  = (int*)(h1b + (size_t)RING * SLOT);
    int* flagL0 = flags;
    int* flagL1 = flagL0 + 64 * FSTR;
    int* flagFC = flagL1 + 128 * FSTR;

    auto cvt = [&](const float* s, u16* d, int n) {
        cvt_kernel<<<(n / 4 + 255) / 256, 256, 0, stream>>>(s, d, n);
    };
    cvt(Wih0, wih0, 4096 * 128);
    cvt(Whh0, whh0, 4096 * 1024);
    cvt(Wih1, wih1, 4096 * 1024);
    cvt(Whh1, whh1, 4096 * 1024);
    cvt(Wfc,  wfc,  128 * 1024);
    cvt(x,    xbuf, B_SZ * S_LEN * V_SZ);
    hipMemsetAsync(h0b + (size_t)(RING - 1) * SLOT, 0, (size_t)BH * sizeof(u16), stream);
    hipMemsetAsync(h1b + (size_t)(RING - 1) * SLOT, 0, (size_t)BH * sizeof(u16), stream);
    hipMemsetAsync(flags, 0, (size_t)196 * FSTR * sizeof(int), stream);

    persist_kernel<<<196, 256, 0, stream>>>(
        xbuf, wih0, whh0, wih1, whh1, wfc,
        bih0, bhh0, bih1, bhh1, bfc,
        h0b, h1b, flagL0, flagL1, flagFC, out);
}